// Round 1
// baseline (814.444 us; speedup 1.0000x reference)
//
#include <hip/hip_runtime.h>
#include <math.h>

#define PI_F 3.14159265358979323846f

// One wave (64 lanes) simulates one batch element's 10-qubit statevector.
// Amplitude index a (10 bits): bits[9:4] = lane, bits[3:0] = register index.
// Wire w corresponds to amplitude bit (9 - w)  [wire 0 = MSB, per reference].
// => wires 0..5 : cross-lane (shfl_xor), wires 6..9 : in-register.

__device__ __forceinline__ float bfly_sum(float v) {
#pragma unroll
  for (int m = 1; m < 64; m <<= 1) v += __shfl_xor(v, m, 64);
  return v;
}

template <int W>
__device__ __forceinline__ void apply_h(float (&sr)[16], float (&si)[16], int lane) {
  const float IS2 = 0.70710678118654752440f;
  if constexpr (W <= 5) {
    constexpr int lb = 5 - W;
    const float sgn = ((lane >> lb) & 1) ? -1.0f : 1.0f;
#pragma unroll
    for (int r = 0; r < 16; ++r) {
      float pr = __shfl_xor(sr[r], 1 << lb, 64);
      float pi = __shfl_xor(si[r], 1 << lb, 64);
      sr[r] = (pr + sgn * sr[r]) * IS2;
      si[r] = (pi + sgn * si[r]) * IS2;
    }
  } else {
    constexpr int rb = 9 - W;
#pragma unroll
    for (int r = 0; r < 16; ++r) {
      if ((r >> rb) & 1) continue;            // compile-time after unroll
      const int r1 = r | (1 << rb);
      float a0r = sr[r], a1r = sr[r1], a0i = si[r], a1i = si[r1];
      sr[r]  = (a0r + a1r) * IS2;  si[r]  = (a0i + a1i) * IS2;
      sr[r1] = (a0r - a1r) * IS2;  si[r1] = (a0i - a1i) * IS2;
    }
  }
}

template <int W>
__device__ __forceinline__ void apply_ry(float (&sr)[16], float (&si)[16], int lane,
                                         float c, float s) {
  if constexpr (W <= 5) {
    constexpr int lb = 5 - W;
    const float t = ((lane >> lb) & 1) ? s : -s;  // bit0: c*a0 - s*a1 ; bit1: c*a1 + s*a0
#pragma unroll
    for (int r = 0; r < 16; ++r) {
      float pr = __shfl_xor(sr[r], 1 << lb, 64);
      float pi = __shfl_xor(si[r], 1 << lb, 64);
      sr[r] = c * sr[r] + t * pr;
      si[r] = c * si[r] + t * pi;
    }
  } else {
    constexpr int rb = 9 - W;
#pragma unroll
    for (int r = 0; r < 16; ++r) {
      if ((r >> rb) & 1) continue;
      const int r1 = r | (1 << rb);
      float a0r = sr[r], a1r = sr[r1], a0i = si[r], a1i = si[r1];
      sr[r]  = c * a0r - s * a1r;  si[r]  = c * a0i - s * a1i;
      sr[r1] = s * a0r + c * a1r;  si[r1] = s * a0i + c * a1i;
    }
  }
}

// multiply amplitudes with wire-W bit == 1 by (cp + i*sp)
template <int W>
__device__ __forceinline__ void apply_phase(float (&sr)[16], float (&si)[16], int lane,
                                            float cp, float sp) {
  if constexpr (W <= 5) {
    constexpr int lb = 5 - W;
    const bool hi = (lane >> lb) & 1;
    const float c = hi ? cp : 1.0f;
    const float s = hi ? sp : 0.0f;
#pragma unroll
    for (int r = 0; r < 16; ++r) {
      float re = sr[r], im = si[r];
      sr[r] = re * c - im * s;
      si[r] = re * s + im * c;
    }
  } else {
    constexpr int rb = 9 - W;
#pragma unroll
    for (int r = 0; r < 16; ++r) {
      if (!((r >> rb) & 1)) continue;
      float re = sr[r], im = si[r];
      sr[r] = re * cp - im * sp;
      si[r] = re * sp + im * cp;
    }
  }
}

// CNOT(control=C, target=C+1)
template <int C>
__device__ __forceinline__ void apply_cnot(float (&sr)[16], float (&si)[16], int lane) {
  if constexpr (C <= 4) {                     // control & target both lane bits
    constexpr int cb = 5 - C;
    constexpr int tb = 4 - C;
    const bool ctrl = (lane >> cb) & 1;
#pragma unroll
    for (int r = 0; r < 16; ++r) {
      float pr = __shfl_xor(sr[r], 1 << tb, 64);
      float pi = __shfl_xor(si[r], 1 << tb, 64);
      sr[r] = ctrl ? pr : sr[r];
      si[r] = ctrl ? pi : si[r];
    }
  } else if constexpr (C == 5) {              // control lane bit 0, target reg bit 3
    const bool ctrl = lane & 1;
#pragma unroll
    for (int r = 0; r < 8; ++r) {
      float t0r = sr[r], t1r = sr[r + 8];
      float t0i = si[r], t1i = si[r + 8];
      sr[r] = ctrl ? t1r : t0r;  sr[r + 8] = ctrl ? t0r : t1r;
      si[r] = ctrl ? t1i : t0i;  si[r + 8] = ctrl ? t0i : t1i;
    }
  } else {                                    // both reg bits: pure register swap
    constexpr int cb = 9 - C;
    constexpr int tb = 8 - C;
#pragma unroll
    for (int r = 0; r < 16; ++r) {
      if (!(((r >> cb) & 1) && !((r >> tb) & 1))) continue;
      const int r1 = r | (1 << tb);
      float tr = sr[r]; sr[r] = sr[r1]; sr[r1] = tr;
      float ti = si[r]; si[r] = si[r1]; si[r1] = ti;
    }
  }
}

__global__ __launch_bounds__(256) void dqc_kernel(
    const float* __restrict__ x, const float* __restrict__ pre_w,
    const float* __restrict__ pre_b, const float* __restrict__ q_params,
    const float* __restrict__ post_w, const float* __restrict__ post_b,
    float* __restrict__ out) {
  const int lane = threadIdx.x & 63;
  const int wave = threadIdx.x >> 6;
  const int b = blockIdx.x * 4 + wave;

  // ---------- pre layer: q_in[w] = tanh(x[b] . pre_w[w] + pre_b[w]) * pi/2
  const float* xb = x + (size_t)b * 512 + lane * 8;
  const float4 xv0 = *(const float4*)(xb);
  const float4 xv1 = *(const float4*)(xb + 4);
  float qin[10];
#pragma unroll
  for (int q = 0; q < 10; ++q) {
    const float* wp = pre_w + q * 512 + lane * 8;
    const float4 w0 = *(const float4*)(wp);
    const float4 w1 = *(const float4*)(wp + 4);
    float a = xv0.x * w0.x + xv0.y * w0.y + xv0.z * w0.z + xv0.w * w0.w +
              xv1.x * w1.x + xv1.y * w1.y + xv1.z * w1.z + xv1.w * w1.w;
    a = bfly_sum(a);
    qin[q] = tanhf(a + pre_b[q]) * (PI_F * 0.5f);
  }

  // ---------- statevector |0...0>
  float sr[16], si[16];
#pragma unroll
  for (int r = 0; r < 16; ++r) { sr[r] = 0.0f; si[r] = 0.0f; }
  sr[0] = (lane == 0) ? 1.0f : 0.0f;

  // ---------- ZZFeatureMap, reps = 2
#pragma unroll 1
  for (int rep = 0; rep < 2; ++rep) {
#define HP(W)                                            \
  {                                                      \
    apply_h<W>(sr, si, lane);                            \
    float ph = 2.0f * qin[W];                            \
    float cp = cosf(ph), sp = sinf(ph);                  \
    apply_phase<W>(sr, si, lane, cp, sp);                \
  }
    HP(0) HP(1) HP(2) HP(3) HP(4) HP(5) HP(6) HP(7) HP(8) HP(9)
#undef HP
#define CPH(I)                                                     \
  {                                                                \
    apply_cnot<I>(sr, si, lane);                                   \
    float ph = 2.0f * (PI_F - qin[I]) * (PI_F - qin[(I) + 1]);     \
    float cp = cosf(ph), sp = sinf(ph);                            \
    apply_phase<(I) + 1>(sr, si, lane, cp, sp);                    \
  }
    CPH(0) CPH(1) CPH(2) CPH(3) CPH(4) CPH(5) CPH(6) CPH(7) CPH(8)
#undef CPH
  }

  // ---------- RealAmplitudes: 6 x (RY layer + CNOT chain)
#pragma unroll 1
  for (int l = 0; l < 6; ++l) {
    const float* qw = q_params + l * 10;
#define RYW(W)                                  \
  {                                             \
    float th = qw[W] * 0.5f;                    \
    float c = cosf(th), s = sinf(th);           \
    apply_ry<W>(sr, si, lane, c, s);            \
  }
    RYW(0) RYW(1) RYW(2) RYW(3) RYW(4) RYW(5) RYW(6) RYW(7) RYW(8) RYW(9)
#undef RYW
    apply_cnot<0>(sr, si, lane); apply_cnot<1>(sr, si, lane);
    apply_cnot<2>(sr, si, lane); apply_cnot<3>(sr, si, lane);
    apply_cnot<4>(sr, si, lane); apply_cnot<5>(sr, si, lane);
    apply_cnot<6>(sr, si, lane); apply_cnot<7>(sr, si, lane);
    apply_cnot<8>(sr, si, lane);
  }

  // ---------- PauliZ expectations + post layer
  float p[16], T = 0.0f;
#pragma unroll
  for (int r = 0; r < 16; ++r) {
    p[r] = sr[r] * sr[r] + si[r] * si[r];
    T += p[r];
  }
  float z[10];
#pragma unroll
  for (int w = 0; w < 6; ++w) {
    const int lb = 5 - w;
    z[w] = ((lane >> lb) & 1) ? -T : T;
  }
#pragma unroll
  for (int w = 6; w < 10; ++w) {
    const int rb = 9 - w;
    float s = 0.0f;
#pragma unroll
    for (int r = 0; r < 16; ++r) s += ((r >> rb) & 1) ? -p[r] : p[r];
    z[w] = s;
  }
#pragma unroll
  for (int w = 0; w < 10; ++w) z[w] = bfly_sum(z[w]);

  if (lane == 0) {
    float o0 = post_b[0], o1 = post_b[1];
#pragma unroll
    for (int w = 0; w < 10; ++w) {
      o0 += z[w] * post_w[w];
      o1 += z[w] * post_w[10 + w];
    }
    *(float2*)(out + (size_t)b * 2) = make_float2(o0, o1);
  }
}

extern "C" void kernel_launch(void* const* d_in, const int* in_sizes, int n_in,
                              void* d_out, int out_size, void* d_ws, size_t ws_size,
                              hipStream_t stream) {
  (void)n_in; (void)d_ws; (void)ws_size; (void)out_size;
  const float* x      = (const float*)d_in[0];
  const float* pre_w  = (const float*)d_in[1];
  const float* pre_b  = (const float*)d_in[2];
  const float* qp     = (const float*)d_in[3];
  const float* post_w = (const float*)d_in[4];
  const float* post_b = (const float*)d_in[5];
  float* out = (float*)d_out;
  const int batch = in_sizes[0] / 512;  // 16384
  dim3 grid(batch / 4), block(256);
  hipLaunchKernelGGL(dqc_kernel, grid, block, 0, stream,
                     x, pre_w, pre_b, qp, post_w, post_b, out);
}

// Round 2
// 322.320 us; speedup vs baseline: 2.5268x; 2.5268x over previous
//
#include <hip/hip_runtime.h>
#include <math.h>

#define PI_F 3.14159265358979323846f

// One wave (64 lanes) simulates one batch element's 10-qubit statevector.
// Amplitude index a (10 bits): bits[9:4] = lane, bits[3:0] = register index.
// Wire w corresponds to amplitude bit (9 - w)  [wire 0 = MSB, per reference].
// => wires 0..5 : cross-lane (ds_swizzle / shfl), wires 6..9 : in-register.

template <int M>
__device__ __forceinline__ float shx(float v) {
  if constexpr (M < 32) {
    // BitMode swizzle: offset = (xor<<10)|(or<<5)|and, and=0x1F. xor<32 never
    // crosses the 32-lane halves, so identical to full-64 shfl_xor.
    return __int_as_float(
        __builtin_amdgcn_ds_swizzle(__float_as_int(v), (M << 10) | 0x1f));
  } else {
    return __shfl_xor(v, 32, 64);
  }
}

__device__ __forceinline__ float bfly_sum(float v) {
  v += shx<1>(v); v += shx<2>(v); v += shx<4>(v);
  v += shx<8>(v); v += shx<16>(v); v += shx<32>(v);
  return v;
}

__device__ __forceinline__ float ftanh(float x) {
  // tanh(x) = 1 - 2/(e^{2x}+1); saturates correctly for large |x|.
  float e = __expf(2.0f * x);
  return 1.0f - 2.0f / (e + 1.0f);
}

template <int W>
__device__ __forceinline__ void apply_h(float (&sr)[16], float (&si)[16], int lane) {
  const float IS2 = 0.70710678118654752440f;
  if constexpr (W <= 5) {
    constexpr int lb = 5 - W;
    const float sgn = ((lane >> lb) & 1) ? -1.0f : 1.0f;
#pragma unroll
    for (int r = 0; r < 16; ++r) {
      float pr = shx<(1 << lb)>(sr[r]);
      float pi = shx<(1 << lb)>(si[r]);
      sr[r] = (pr + sgn * sr[r]) * IS2;
      si[r] = (pi + sgn * si[r]) * IS2;
    }
  } else {
    constexpr int rb = 9 - W;
#pragma unroll
    for (int r = 0; r < 16; ++r) {
      if ((r >> rb) & 1) continue;            // compile-time after unroll
      const int r1 = r | (1 << rb);
      float a0r = sr[r], a1r = sr[r1], a0i = si[r], a1i = si[r1];
      sr[r]  = (a0r + a1r) * IS2;  si[r]  = (a0i + a1i) * IS2;
      sr[r1] = (a0r - a1r) * IS2;  si[r1] = (a0i - a1i) * IS2;
    }
  }
}

template <int W>
__device__ __forceinline__ void apply_ry(float (&sr)[16], float (&si)[16], int lane,
                                         float c, float s) {
  if constexpr (W <= 5) {
    constexpr int lb = 5 - W;
    const float t = ((lane >> lb) & 1) ? s : -s;  // bit0: c*a0 - s*a1 ; bit1: c*a1 + s*a0
#pragma unroll
    for (int r = 0; r < 16; ++r) {
      float pr = shx<(1 << lb)>(sr[r]);
      float pi = shx<(1 << lb)>(si[r]);
      sr[r] = c * sr[r] + t * pr;
      si[r] = c * si[r] + t * pi;
    }
  } else {
    constexpr int rb = 9 - W;
#pragma unroll
    for (int r = 0; r < 16; ++r) {
      if ((r >> rb) & 1) continue;
      const int r1 = r | (1 << rb);
      float a0r = sr[r], a1r = sr[r1], a0i = si[r], a1i = si[r1];
      sr[r]  = c * a0r - s * a1r;  si[r]  = c * a0i - s * a1i;
      sr[r1] = s * a0r + c * a1r;  si[r1] = s * a0i + c * a1i;
    }
  }
}

// multiply amplitudes with wire-W bit == 1 by (cp + i*sp)
template <int W>
__device__ __forceinline__ void apply_phase(float (&sr)[16], float (&si)[16], int lane,
                                            float cp, float sp) {
  if constexpr (W <= 5) {
    constexpr int lb = 5 - W;
    const bool hi = (lane >> lb) & 1;
    const float c = hi ? cp : 1.0f;
    const float s = hi ? sp : 0.0f;
#pragma unroll
    for (int r = 0; r < 16; ++r) {
      float re = sr[r], im = si[r];
      sr[r] = re * c - im * s;
      si[r] = re * s + im * c;
    }
  } else {
    constexpr int rb = 9 - W;
#pragma unroll
    for (int r = 0; r < 16; ++r) {
      if (!((r >> rb) & 1)) continue;
      float re = sr[r], im = si[r];
      sr[r] = re * cp - im * sp;
      si[r] = re * sp + im * cp;
    }
  }
}

// CNOT(control=C, target=C+1)
template <int C>
__device__ __forceinline__ void apply_cnot(float (&sr)[16], float (&si)[16], int lane) {
  if constexpr (C <= 4) {                     // control & target both lane bits
    constexpr int cb = 5 - C;
    constexpr int tb = 4 - C;
    const bool ctrl = (lane >> cb) & 1;
#pragma unroll
    for (int r = 0; r < 16; ++r) {
      float pr = shx<(1 << tb)>(sr[r]);
      float pi = shx<(1 << tb)>(si[r]);
      sr[r] = ctrl ? pr : sr[r];
      si[r] = ctrl ? pi : si[r];
    }
  } else if constexpr (C == 5) {              // control lane bit 0, target reg bit 3
    const bool ctrl = lane & 1;
#pragma unroll
    for (int r = 0; r < 8; ++r) {
      float t0r = sr[r], t1r = sr[r + 8];
      float t0i = si[r], t1i = si[r + 8];
      sr[r] = ctrl ? t1r : t0r;  sr[r + 8] = ctrl ? t0r : t1r;
      si[r] = ctrl ? t1i : t0i;  si[r + 8] = ctrl ? t0i : t1i;
    }
  } else {                                    // both reg bits: pure register swap
    constexpr int cb = 9 - C;
    constexpr int tb = 8 - C;
#pragma unroll
    for (int r = 0; r < 16; ++r) {
      if (!(((r >> cb) & 1) && !((r >> tb) & 1))) continue;
      const int r1 = r | (1 << tb);
      float tr = sr[r]; sr[r] = sr[r1]; sr[r1] = tr;
      float ti = si[r]; si[r] = si[r1]; si[r1] = ti;
    }
  }
}

// Batch-uniform RA-layer trig table: tab[0..59] = cos(qp*0.5), tab[60..119] = sin.
__global__ void dqc_trig_kernel(const float* __restrict__ qp, float* __restrict__ tab) {
  int t = threadIdx.x;
  if (t < 60) {
    float th = qp[t] * 0.5f;
    tab[t]      = __cosf(th);
    tab[60 + t] = __sinf(th);
  }
}

__global__ __launch_bounds__(256, 4) void dqc_kernel(
    const float* __restrict__ x, const float* __restrict__ pre_w,
    const float* __restrict__ pre_b, const float* __restrict__ q_params,
    const float* __restrict__ post_w, const float* __restrict__ post_b,
    const float* __restrict__ tab, float* __restrict__ out) {
  const int lane = threadIdx.x & 63;
  const int wave = threadIdx.x >> 6;
  const int b = blockIdx.x * 4 + wave;

  // ---------- pre layer: q_in[w] = tanh(x[b] . pre_w[w] + pre_b[w]) * pi/2
  const float* xb = x + (size_t)b * 512 + lane * 8;
  const float4 xv0 = *(const float4*)(xb);
  const float4 xv1 = *(const float4*)(xb + 4);
  float qin[10];
#pragma unroll
  for (int q = 0; q < 10; ++q) {
    const float* wp = pre_w + q * 512 + lane * 8;
    const float4 w0 = *(const float4*)(wp);
    const float4 w1 = *(const float4*)(wp + 4);
    float a = xv0.x * w0.x + xv0.y * w0.y + xv0.z * w0.z + xv0.w * w0.w +
              xv1.x * w1.x + xv1.y * w1.y + xv1.z * w1.z + xv1.w * w1.w;
    a = bfly_sum(a);
    qin[q] = ftanh(a + pre_b[q]) * (PI_F * 0.5f);
  }

  // ---------- statevector |0...0>
  float sr[16], si[16];
#pragma unroll
  for (int r = 0; r < 16; ++r) { sr[r] = 0.0f; si[r] = 0.0f; }
  sr[0] = (lane == 0) ? 1.0f : 0.0f;

  // ---------- ZZFeatureMap, reps = 2
#pragma unroll 1
  for (int rep = 0; rep < 2; ++rep) {
#define HP(W)                                            \
  {                                                      \
    apply_h<W>(sr, si, lane);                            \
    float ph = 2.0f * qin[W];                            \
    float cp = __cosf(ph), sp = __sinf(ph);              \
    apply_phase<W>(sr, si, lane, cp, sp);                \
  }
    HP(0) HP(1) HP(2) HP(3) HP(4) HP(5) HP(6) HP(7) HP(8) HP(9)
#undef HP
#define CPH(I)                                                     \
  {                                                                \
    apply_cnot<I>(sr, si, lane);                                   \
    float ph = 2.0f * (PI_F - qin[I]) * (PI_F - qin[(I) + 1]);     \
    float cp = __cosf(ph), sp = __sinf(ph);                        \
    apply_phase<(I) + 1>(sr, si, lane, cp, sp);                    \
  }
    CPH(0) CPH(1) CPH(2) CPH(3) CPH(4) CPH(5) CPH(6) CPH(7) CPH(8)
#undef CPH
  }

  // ---------- RealAmplitudes: 6 x (RY layer + CNOT chain)
#pragma unroll 1
  for (int l = 0; l < 6; ++l) {
    float qc[10], qs[10];
    if (tab) {
#pragma unroll
      for (int w = 0; w < 10; ++w) {
        qc[w] = tab[l * 10 + w];
        qs[w] = tab[60 + l * 10 + w];
      }
    } else {
#pragma unroll
      for (int w = 0; w < 10; ++w) {
        float th = q_params[l * 10 + w] * 0.5f;
        qc[w] = __cosf(th);
        qs[w] = __sinf(th);
      }
    }
#define RYW(W) apply_ry<W>(sr, si, lane, qc[W], qs[W]);
    RYW(0) RYW(1) RYW(2) RYW(3) RYW(4) RYW(5) RYW(6) RYW(7) RYW(8) RYW(9)
#undef RYW
    apply_cnot<0>(sr, si, lane); apply_cnot<1>(sr, si, lane);
    apply_cnot<2>(sr, si, lane); apply_cnot<3>(sr, si, lane);
    apply_cnot<4>(sr, si, lane); apply_cnot<5>(sr, si, lane);
    apply_cnot<6>(sr, si, lane); apply_cnot<7>(sr, si, lane);
    apply_cnot<8>(sr, si, lane);
  }

  // ---------- PauliZ expectations + post layer
  float p[16], T = 0.0f;
#pragma unroll
  for (int r = 0; r < 16; ++r) {
    p[r] = sr[r] * sr[r] + si[r] * si[r];
    T += p[r];
  }
  float z[10];
#pragma unroll
  for (int w = 0; w < 6; ++w) {
    const int lb = 5 - w;
    z[w] = ((lane >> lb) & 1) ? -T : T;
  }
#pragma unroll
  for (int w = 6; w < 10; ++w) {
    const int rb = 9 - w;
    float s = 0.0f;
#pragma unroll
    for (int r = 0; r < 16; ++r) s += ((r >> rb) & 1) ? -p[r] : p[r];
    z[w] = s;
  }
#pragma unroll
  for (int w = 0; w < 10; ++w) z[w] = bfly_sum(z[w]);

  if (lane == 0) {
    float o0 = post_b[0], o1 = post_b[1];
#pragma unroll
    for (int w = 0; w < 10; ++w) {
      o0 += z[w] * post_w[w];
      o1 += z[w] * post_w[10 + w];
    }
    *(float2*)(out + (size_t)b * 2) = make_float2(o0, o1);
  }
}

extern "C" void kernel_launch(void* const* d_in, const int* in_sizes, int n_in,
                              void* d_out, int out_size, void* d_ws, size_t ws_size,
                              hipStream_t stream) {
  (void)n_in; (void)out_size;
  const float* x      = (const float*)d_in[0];
  const float* pre_w  = (const float*)d_in[1];
  const float* pre_b  = (const float*)d_in[2];
  const float* qp     = (const float*)d_in[3];
  const float* post_w = (const float*)d_in[4];
  const float* post_b = (const float*)d_in[5];
  float* out = (float*)d_out;

  float* tab = nullptr;
  if (ws_size >= 120 * sizeof(float)) {
    tab = (float*)d_ws;
    hipLaunchKernelGGL(dqc_trig_kernel, dim3(1), dim3(64), 0, stream, qp, tab);
  }

  const int batch = in_sizes[0] / 512;  // 16384
  dim3 grid(batch / 4), block(256);
  hipLaunchKernelGGL(dqc_kernel, grid, block, 0, stream,
                     x, pre_w, pre_b, qp, post_w, post_b, tab, out);
}

// Round 3
// 306.605 us; speedup vs baseline: 2.6563x; 1.0513x over previous
//
#include <hip/hip_runtime.h>
#include <math.h>

#define PI_F 3.14159265358979323846f

// One wave (64 lanes) simulates one batch element's 10-qubit statevector.
// Amplitude index a (10 bits): bits[9:4] = lane, bits[3:0] = register index.
// Wire w corresponds to amplitude bit (9 - w)  [wire 0 = MSB, per reference].
// => wires 0..5 : cross-lane (ds_swizzle / shfl), wires 6..9 : in-register.

template <int M>
__device__ __forceinline__ float shx(float v) {
  if constexpr (M < 32) {
    // BitMode swizzle: offset = (xor<<10)|(or<<5)|and, and=0x1F. xor<32 never
    // crosses the 32-lane halves, so identical to full-64 shfl_xor.
    return __int_as_float(
        __builtin_amdgcn_ds_swizzle(__float_as_int(v), (M << 10) | 0x1f));
  } else {
    return __shfl_xor(v, 32, 64);
  }
}

__device__ __forceinline__ float bfly_sum(float v) {
  v += shx<1>(v); v += shx<2>(v); v += shx<4>(v);
  v += shx<8>(v); v += shx<16>(v); v += shx<32>(v);
  return v;
}

__device__ __forceinline__ float ftanh(float x) {
  // tanh(x) = 1 - 2/(e^{2x}+1); saturates correctly for large |x|.
  float e = __expf(2.0f * x);
  return 1.0f - 2.0f / (e + 1.0f);
}

template <int W>
__device__ __forceinline__ void apply_h(float (&sr)[16], float (&si)[16], int lane) {
  const float IS2 = 0.70710678118654752440f;
  if constexpr (W <= 5) {
    constexpr int lb = 5 - W;
    const float sgn = ((lane >> lb) & 1) ? -IS2 : IS2;
#pragma unroll
    for (int r = 0; r < 16; ++r) {
      float pr = shx<(1 << lb)>(sr[r]);
      float pi = shx<(1 << lb)>(si[r]);
      sr[r] = pr * IS2 + sgn * sr[r];
      si[r] = pi * IS2 + sgn * si[r];
    }
  } else {
    constexpr int rb = 9 - W;
#pragma unroll
    for (int r = 0; r < 16; ++r) {
      if ((r >> rb) & 1) continue;            // compile-time after unroll
      const int r1 = r | (1 << rb);
      float a0r = sr[r], a1r = sr[r1], a0i = si[r], a1i = si[r1];
      sr[r]  = (a0r + a1r) * IS2;  si[r]  = (a0i + a1i) * IS2;
      sr[r1] = (a0r - a1r) * IS2;  si[r1] = (a0i - a1i) * IS2;
    }
  }
}

template <int W>
__device__ __forceinline__ void apply_ry(float (&sr)[16], float (&si)[16], int lane,
                                         float c, float s) {
  if constexpr (W <= 5) {
    constexpr int lb = 5 - W;
    const float t = ((lane >> lb) & 1) ? s : -s;  // bit0: c*a0 - s*a1 ; bit1: c*a1 + s*a0
#pragma unroll
    for (int r = 0; r < 16; ++r) {
      float pr = shx<(1 << lb)>(sr[r]);
      float pi = shx<(1 << lb)>(si[r]);
      sr[r] = c * sr[r] + t * pr;
      si[r] = c * si[r] + t * pi;
    }
  } else {
    constexpr int rb = 9 - W;
#pragma unroll
    for (int r = 0; r < 16; ++r) {
      if ((r >> rb) & 1) continue;
      const int r1 = r | (1 << rb);
      float a0r = sr[r], a1r = sr[r1], a0i = si[r], a1i = si[r1];
      sr[r]  = c * a0r - s * a1r;  si[r]  = c * a0i - s * a1i;
      sr[r1] = s * a0r + c * a1r;  si[r1] = s * a0i + c * a1i;
    }
  }
}

// multiply amplitudes with wire-W bit == 1 by (cp + i*sp)
template <int W>
__device__ __forceinline__ void apply_phase(float (&sr)[16], float (&si)[16], int lane,
                                            float cp, float sp) {
  if constexpr (W <= 5) {
    constexpr int lb = 5 - W;
    const bool hi = (lane >> lb) & 1;
    const float c = hi ? cp : 1.0f;
    const float s = hi ? sp : 0.0f;
#pragma unroll
    for (int r = 0; r < 16; ++r) {
      float re = sr[r], im = si[r];
      sr[r] = re * c - im * s;
      si[r] = re * s + im * c;
    }
  } else {
    constexpr int rb = 9 - W;
#pragma unroll
    for (int r = 0; r < 16; ++r) {
      if (!((r >> rb) & 1)) continue;
      float re = sr[r], im = si[r];
      sr[r] = re * cp - im * sp;
      si[r] = re * sp + im * cp;
    }
  }
}

// CNOT(control=C, target=C+1)
template <int C>
__device__ __forceinline__ void apply_cnot(float (&sr)[16], float (&si)[16], int lane) {
  if constexpr (C <= 4) {                     // control & target both lane bits
    constexpr int cb = 5 - C;
    constexpr int tb = 4 - C;
    const bool ctrl = (lane >> cb) & 1;
#pragma unroll
    for (int r = 0; r < 16; ++r) {
      float pr = shx<(1 << tb)>(sr[r]);
      float pi = shx<(1 << tb)>(si[r]);
      sr[r] = ctrl ? pr : sr[r];
      si[r] = ctrl ? pi : si[r];
    }
  } else if constexpr (C == 5) {              // control lane bit 0, target reg bit 3
    const bool ctrl = lane & 1;
#pragma unroll
    for (int r = 0; r < 8; ++r) {
      float t0r = sr[r], t1r = sr[r + 8];
      float t0i = si[r], t1i = si[r + 8];
      sr[r] = ctrl ? t1r : t0r;  sr[r + 8] = ctrl ? t0r : t1r;
      si[r] = ctrl ? t1i : t0i;  si[r + 8] = ctrl ? t0i : t1i;
    }
  } else {                                    // both reg bits: pure register swap
    constexpr int cb = 9 - C;
    constexpr int tb = 8 - C;
#pragma unroll
    for (int r = 0; r < 16; ++r) {
      if (!(((r >> cb) & 1) && !((r >> tb) & 1))) continue;
      const int r1 = r | (1 << tb);
      float tr = sr[r]; sr[r] = sr[r1]; sr[r1] = tr;
      float ti = si[r]; si[r] = si[r1]; si[r1] = ti;
    }
  }
}

// Batch-uniform RA-layer trig table: tab[0..59] = cos(qp*0.5), tab[60..119] = sin.
__global__ void dqc_trig_kernel(const float* __restrict__ qp, float* __restrict__ tab) {
  int t = threadIdx.x;
  if (t < 60) {
    float th = qp[t] * 0.5f;
    tab[t]      = __cosf(th);
    tab[60 + t] = __sinf(th);
  }
}

__global__ __launch_bounds__(256) void dqc_kernel(
    const float* __restrict__ x, const float* __restrict__ pre_w,
    const float* __restrict__ pre_b, const float* __restrict__ q_params,
    const float* __restrict__ post_w, const float* __restrict__ post_b,
    const float* __restrict__ tab, float* __restrict__ out) {
  const int lane = threadIdx.x & 63;
  const int wave = threadIdx.x >> 6;
  const int b = blockIdx.x * 4 + wave;

  // ---------- pre layer: q_in[w] = tanh(x[b] . pre_w[w] + pre_b[w]) * pi/2
  const float* xb = x + (size_t)b * 512 + lane * 8;
  const float4 xv0 = *(const float4*)(xb);
  const float4 xv1 = *(const float4*)(xb + 4);
  float qin[10];
#pragma unroll
  for (int q = 0; q < 10; ++q) {
    const float* wp = pre_w + q * 512 + lane * 8;
    const float4 w0 = *(const float4*)(wp);
    const float4 w1 = *(const float4*)(wp + 4);
    float a = xv0.x * w0.x + xv0.y * w0.y + xv0.z * w0.z + xv0.w * w0.w +
              xv1.x * w1.x + xv1.y * w1.y + xv1.z * w1.z + xv1.w * w1.w;
    a = bfly_sum(a);
    qin[q] = ftanh(a + pre_b[q]) * (PI_F * 0.5f);
  }

  // ---------- statevector |0...0>
  float sr[16], si[16];
#pragma unroll
  for (int r = 0; r < 16; ++r) { sr[r] = 0.0f; si[r] = 0.0f; }
  sr[0] = (lane == 0) ? 1.0f : 0.0f;

  // ---------- ZZFeatureMap, reps = 2
#pragma unroll 1
  for (int rep = 0; rep < 2; ++rep) {
#define HP(W)                                            \
  {                                                      \
    apply_h<W>(sr, si, lane);                            \
    float ph = 2.0f * qin[W];                            \
    float cp = __cosf(ph), sp = __sinf(ph);              \
    apply_phase<W>(sr, si, lane, cp, sp);                \
  }
    HP(0) HP(1) HP(2) HP(3) HP(4) HP(5) HP(6) HP(7) HP(8) HP(9)
#undef HP
#define CPH(I)                                                     \
  {                                                                \
    apply_cnot<I>(sr, si, lane);                                   \
    float ph = 2.0f * (PI_F - qin[I]) * (PI_F - qin[(I) + 1]);     \
    float cp = __cosf(ph), sp = __sinf(ph);                        \
    apply_phase<(I) + 1>(sr, si, lane, cp, sp);                    \
  }
    CPH(0) CPH(1) CPH(2) CPH(3) CPH(4) CPH(5) CPH(6) CPH(7) CPH(8)
#undef CPH
  }

  // ---------- RealAmplitudes: 6 x (RY layer + CNOT chain)
#pragma unroll 1
  for (int l = 0; l < 6; ++l) {
    float qc[10], qs[10];
    if (tab) {
#pragma unroll
      for (int w = 0; w < 10; ++w) {
        qc[w] = tab[l * 10 + w];
        qs[w] = tab[60 + l * 10 + w];
      }
    } else {
#pragma unroll
      for (int w = 0; w < 10; ++w) {
        float th = q_params[l * 10 + w] * 0.5f;
        qc[w] = __cosf(th);
        qs[w] = __sinf(th);
      }
    }
#define RYW(W) apply_ry<W>(sr, si, lane, qc[W], qs[W]);
    RYW(0) RYW(1) RYW(2) RYW(3) RYW(4) RYW(5) RYW(6) RYW(7) RYW(8) RYW(9)
#undef RYW
    apply_cnot<0>(sr, si, lane); apply_cnot<1>(sr, si, lane);
    apply_cnot<2>(sr, si, lane); apply_cnot<3>(sr, si, lane);
    apply_cnot<4>(sr, si, lane); apply_cnot<5>(sr, si, lane);
    apply_cnot<6>(sr, si, lane); apply_cnot<7>(sr, si, lane);
    apply_cnot<8>(sr, si, lane);
  }

  // ---------- PauliZ expectations + post layer
  float p[16], T = 0.0f;
#pragma unroll
  for (int r = 0; r < 16; ++r) {
    p[r] = sr[r] * sr[r] + si[r] * si[r];
    T += p[r];
  }
  float z[10];
#pragma unroll
  for (int w = 0; w < 6; ++w) {
    const int lb = 5 - w;
    z[w] = ((lane >> lb) & 1) ? -T : T;
  }
#pragma unroll
  for (int w = 6; w < 10; ++w) {
    const int rb = 9 - w;
    float s = 0.0f;
#pragma unroll
    for (int r = 0; r < 16; ++r) s += ((r >> rb) & 1) ? -p[r] : p[r];
    z[w] = s;
  }
#pragma unroll
  for (int w = 0; w < 10; ++w) z[w] = bfly_sum(z[w]);

  if (lane == 0) {
    float o0 = post_b[0], o1 = post_b[1];
#pragma unroll
    for (int w = 0; w < 10; ++w) {
      o0 += z[w] * post_w[w];
      o1 += z[w] * post_w[10 + w];
    }
    *(float2*)(out + (size_t)b * 2) = make_float2(o0, o1);
  }
}

extern "C" void kernel_launch(void* const* d_in, const int* in_sizes, int n_in,
                              void* d_out, int out_size, void* d_ws, size_t ws_size,
                              hipStream_t stream) {
  (void)n_in; (void)out_size;
  const float* x      = (const float*)d_in[0];
  const float* pre_w  = (const float*)d_in[1];
  const float* pre_b  = (const float*)d_in[2];
  const float* qp     = (const float*)d_in[3];
  const float* post_w = (const float*)d_in[4];
  const float* post_b = (const float*)d_in[5];
  float* out = (float*)d_out;

  float* tab = nullptr;
  if (ws_size >= 120 * sizeof(float)) {
    tab = (float*)d_ws;
    hipLaunchKernelGGL(dqc_trig_kernel, dim3(1), dim3(64), 0, stream, qp, tab);
  }

  const int batch = in_sizes[0] / 512;  // 16384
  dim3 grid(batch / 4), block(256);
  hipLaunchKernelGGL(dqc_kernel, grid, block, 0, stream,
                     x, pre_w, pre_b, qp, post_w, post_b, tab, out);
}

// Round 4
// 174.008 us; speedup vs baseline: 4.6805x; 1.7620x over previous
//
#include <hip/hip_runtime.h>
#include <math.h>

#define PI_F 3.14159265358979323846f

// One wave (64 lanes) simulates one batch element's 10-qubit statevector.
// Amplitude index a (10 bits): bits[9:4] = lane, bits[3:0] = register index.
// Wire w corresponds to amplitude bit (9 - w)  [wire 0 = MSB, per reference].
// => wires 0..5 : cross-lane, wires 6..9 : in-register.
//
// Algebraic structure used here:
//  - ZZFM rep 1 from |0>: H-layer -> uniform; all phases diagonal; CNOT chain
//    is the prefix-xor bit permutation. Final: amp(y) = e^{i*theta1(y)},
//    theta1(y) = sum_w 2 qin_w (y_{w-1}^y_w) + sum_i phi_i y_{i+1}.
//  - ZZFM rep 2: physical H-layer, ONE folded diagonal phase
//    theta2(a) = sum_w 2 qin_w b_w + sum_i phi_i p_{i+1} (p = prefix parity),
//    then the pure CNOT cascade.
//  - CNOT cascade on lane wires == ds_bpermute with addr = gray(lane).
//  - All H gates are RAW (+/- butterflies); the 2^-10 amplitude scale is
//    deferred: probs carry 2^20, removed by SC in the epilogue.

template <int M>
__device__ __forceinline__ float shx(float v) {
  if constexpr (M < 32) {
    return __int_as_float(
        __builtin_amdgcn_ds_swizzle(__float_as_int(v), (M << 10) | 0x1f));
  } else {
    return __shfl_xor(v, 32, 64);
  }
}

__device__ __forceinline__ float bfly_sum(float v) {
  v += shx<1>(v); v += shx<2>(v); v += shx<4>(v);
  v += shx<8>(v); v += shx<16>(v); v += shx<32>(v);
  return v;
}

__device__ __forceinline__ float ftanh(float x) {
  float e = __expf(2.0f * x);
  return 1.0f - 2.0f / (e + 1.0f);
}

// RAW Hadamard (no 1/sqrt2): out0 = a0+a1, out1 = a0-a1
template <int W>
__device__ __forceinline__ void apply_h(float (&sr)[16], float (&si)[16], int lane) {
  if constexpr (W <= 5) {
    constexpr int lb = 5 - W;
    const float sgn = ((lane >> lb) & 1) ? -1.0f : 1.0f;
#pragma unroll
    for (int r = 0; r < 16; ++r) {
      float pr = shx<(1 << lb)>(sr[r]);
      float pi = shx<(1 << lb)>(si[r]);
      sr[r] = pr + sgn * sr[r];
      si[r] = pi + sgn * si[r];
    }
  } else {
    constexpr int rb = 9 - W;
#pragma unroll
    for (int r = 0; r < 16; ++r) {
      if ((r >> rb) & 1) continue;
      const int r1 = r | (1 << rb);
      float a0r = sr[r], a1r = sr[r1], a0i = si[r], a1i = si[r1];
      sr[r]  = a0r + a1r;  si[r]  = a0i + a1i;
      sr[r1] = a0r - a1r;  si[r1] = a0i - a1i;
    }
  }
}

template <int W>
__device__ __forceinline__ void apply_ry(float (&sr)[16], float (&si)[16], int lane,
                                         float c, float s) {
  if constexpr (W <= 5) {
    constexpr int lb = 5 - W;
    const float t = ((lane >> lb) & 1) ? s : -s;
#pragma unroll
    for (int r = 0; r < 16; ++r) {
      float pr = shx<(1 << lb)>(sr[r]);
      float pi = shx<(1 << lb)>(si[r]);
      sr[r] = c * sr[r] + t * pr;
      si[r] = c * si[r] + t * pi;
    }
  } else {
    constexpr int rb = 9 - W;
#pragma unroll
    for (int r = 0; r < 16; ++r) {
      if ((r >> rb) & 1) continue;
      const int r1 = r | (1 << rb);
      float a0r = sr[r], a1r = sr[r1], a0i = si[r], a1i = si[r1];
      sr[r]  = c * a0r - s * a1r;  si[r]  = c * a0i - s * a1i;
      sr[r1] = s * a0r + c * a1r;  si[r1] = s * a0i + c * a1i;
    }
  }
}

// CNOT(control=C, target=C+1), used only for C >= 5 (reg-side tail of cascade)
template <int C>
__device__ __forceinline__ void apply_cnot(float (&sr)[16], float (&si)[16], int lane) {
  if constexpr (C == 5) {                     // control lane bit 0, target reg bit 3
    const bool ctrl = lane & 1;
#pragma unroll
    for (int r = 0; r < 8; ++r) {
      float t0r = sr[r], t1r = sr[r + 8];
      float t0i = si[r], t1i = si[r + 8];
      sr[r] = ctrl ? t1r : t0r;  sr[r + 8] = ctrl ? t0r : t1r;
      si[r] = ctrl ? t1i : t0i;  si[r + 8] = ctrl ? t0i : t1i;
    }
  } else {                                    // both reg bits: pure SSA renaming
    constexpr int cb = 9 - C;
    constexpr int tb = 8 - C;
#pragma unroll
    for (int r = 0; r < 16; ++r) {
      if (!(((r >> cb) & 1) && !((r >> tb) & 1))) continue;
      const int r1 = r | (1 << tb);
      float tr = sr[r]; sr[r] = sr[r1]; sr[r1] = tr;
      float ti = si[r]; si[r] = si[r1]; si[r1] = ti;
    }
  }
}

// Full CNOT cascade C(0,1)..C(8,9): lane-wire part is the Gray permutation.
__device__ __forceinline__ void cascade(float (&sr)[16], float (&si)[16], int lane) {
  const int addr = ((lane ^ (lane >> 1)) << 2);
#pragma unroll
  for (int r = 0; r < 16; ++r) {
    sr[r] = __int_as_float(__builtin_amdgcn_ds_bpermute(addr, __float_as_int(sr[r])));
    si[r] = __int_as_float(__builtin_amdgcn_ds_bpermute(addr, __float_as_int(si[r])));
  }
  apply_cnot<5>(sr, si, lane);
  apply_cnot<6>(sr, si, lane);
  apply_cnot<7>(sr, si, lane);
  apply_cnot<8>(sr, si, lane);
}

// Batch-uniform RA-layer trig table: tab[0..59] = cos(qp*0.5), tab[60..119] = sin.
__global__ void dqc_trig_kernel(const float* __restrict__ qp, float* __restrict__ tab) {
  int t = threadIdx.x;
  if (t < 60) {
    float th = qp[t] * 0.5f;
    tab[t]      = __cosf(th);
    tab[60 + t] = __sinf(th);
  }
}

__global__ __launch_bounds__(256) void dqc_kernel(
    const float* __restrict__ x, const float* __restrict__ pre_w,
    const float* __restrict__ pre_b, const float* __restrict__ q_params,
    const float* __restrict__ post_w, const float* __restrict__ post_b,
    const float* __restrict__ tab, float* __restrict__ out) {
  const int lane = threadIdx.x & 63;
  const int wave = threadIdx.x >> 6;
  const int b = blockIdx.x * 4 + wave;

  // ---------- pre layer: q_in[w] = tanh(x[b] . pre_w[w] + pre_b[w]) * pi/2
  const float* xb = x + (size_t)b * 512 + lane * 8;
  const float4 xv0 = *(const float4*)(xb);
  const float4 xv1 = *(const float4*)(xb + 4);
  float qin[10];
#pragma unroll
  for (int q = 0; q < 10; ++q) {
    const float* wp = pre_w + q * 512 + lane * 8;
    const float4 w0 = *(const float4*)(wp);
    const float4 w1 = *(const float4*)(wp + 4);
    float a = xv0.x * w0.x + xv0.y * w0.y + xv0.z * w0.z + xv0.w * w0.w +
              xv1.x * w1.x + xv1.y * w1.y + xv1.z * w1.z + xv1.w * w1.w;
    a = bfly_sum(a);
    qin[q] = ftanh(a + pre_b[q]) * (PI_F * 0.5f);
  }

  // angle constants (all wave-uniform)
  float tq[10], phi[9];
#pragma unroll
  for (int w = 0; w < 10; ++w) tq[w] = 2.0f * qin[w];
#pragma unroll
  for (int i = 0; i < 9; ++i)
    phi[i] = 2.0f * (PI_F - qin[i]) * (PI_F - qin[i + 1]);

  float sr[16], si[16];

  // ---------- ZZFM rep 1 (analytic): amp(y) = e^{i*theta1(y)}
  {
    float A1 = 0.0f;
    int bprev = 0;
#pragma unroll
    for (int w = 0; w <= 5; ++w) {
      int bw = (lane >> (5 - w)) & 1;
      A1 += (bw ^ bprev) ? tq[w] : 0.0f;
      bprev = bw;
    }
#pragma unroll
    for (int i = 0; i <= 4; ++i)
      A1 += ((lane >> (5 - (i + 1))) & 1) ? phi[i] : 0.0f;
    const int b5 = lane & 1;
    const float m0 = A1 + (b5 ? tq[6] : 0.0f);   // for regs with bit6 = 0
    const float m1 = A1 + (b5 ? 0.0f : tq[6]);   // for regs with bit6 = 1
#pragma unroll
    for (int r = 0; r < 16; ++r) {
      const int c6 = (r >> 3) & 1, c7 = (r >> 2) & 1, c8 = (r >> 1) & 1, c9 = r & 1;
      float S = ((c6 ^ c7) ? tq[7] : 0.0f) + ((c7 ^ c8) ? tq[8] : 0.0f) +
                ((c8 ^ c9) ? tq[9] : 0.0f) +
                (c6 ? phi[5] : 0.0f) + (c7 ? phi[6] : 0.0f) +
                (c8 ? phi[7] : 0.0f) + (c9 ? phi[8] : 0.0f);
      float th = (c6 ? m1 : m0) + S;
      sr[r] = __cosf(th);
      si[r] = __sinf(th);
    }
  }

  // ---------- ZZFM rep 2: H layer (raw), folded diagonal, cascade
  apply_h<0>(sr, si, lane); apply_h<1>(sr, si, lane); apply_h<2>(sr, si, lane);
  apply_h<3>(sr, si, lane); apply_h<4>(sr, si, lane); apply_h<5>(sr, si, lane);
  apply_h<6>(sr, si, lane); apply_h<7>(sr, si, lane); apply_h<8>(sr, si, lane);
  apply_h<9>(sr, si, lane);
  {
    float A2 = 0.0f;
    int pfx = 0;
#pragma unroll
    for (int w = 0; w <= 5; ++w) {
      int bw = (lane >> (5 - w)) & 1;
      A2 += bw ? tq[w] : 0.0f;
      pfx ^= bw;
      if (w >= 1) A2 += pfx ? phi[w - 1] : 0.0f;   // phi_{w-1} * p_w
    }
    const bool Lb = pfx;                           // lane parity
#pragma unroll
    for (int r = 0; r < 16; ++r) {
      const int c6 = (r >> 3) & 1, c7 = (r >> 2) & 1, c8 = (r >> 1) & 1, c9 = r & 1;
      const int q6 = c6, q7 = q6 ^ c7, q8 = q7 ^ c8, q9 = q8 ^ c9;
      float S2 = (c6 ? tq[6] : 0.0f) + (c7 ? tq[7] : 0.0f) +
                 (c8 ? tq[8] : 0.0f) + (c9 ? tq[9] : 0.0f);
      float V = (q6 ? phi[5] : 0.0f) + (q7 ? phi[6] : 0.0f) +
                (q8 ? phi[7] : 0.0f) + (q9 ? phi[8] : 0.0f);
      float U = (q6 ? 0.0f : phi[5]) + (q7 ? 0.0f : phi[6]) +
                (q8 ? 0.0f : phi[7]) + (q9 ? 0.0f : phi[8]);
      float th = A2 + (Lb ? (S2 + U) : (S2 + V));
      float c = __cosf(th), s = __sinf(th);
      float nr = sr[r] * c - si[r] * s;
      si[r]    = sr[r] * s + si[r] * c;
      sr[r] = nr;
    }
  }
  cascade(sr, si, lane);

  // ---------- RealAmplitudes: 6 x (RY layer + CNOT cascade)
#pragma unroll 1
  for (int l = 0; l < 6; ++l) {
    float qc[10], qs[10];
    if (tab) {
#pragma unroll
      for (int w = 0; w < 10; ++w) {
        qc[w] = tab[l * 10 + w];
        qs[w] = tab[60 + l * 10 + w];
      }
    } else {
#pragma unroll
      for (int w = 0; w < 10; ++w) {
        float th = q_params[l * 10 + w] * 0.5f;
        qc[w] = __cosf(th);
        qs[w] = __sinf(th);
      }
    }
#define RYW(W) apply_ry<W>(sr, si, lane, qc[W], qs[W]);
    RYW(0) RYW(1) RYW(2) RYW(3) RYW(4) RYW(5) RYW(6) RYW(7) RYW(8) RYW(9)
#undef RYW
    cascade(sr, si, lane);
  }

  // ---------- PauliZ expectations + post layer (state carries 2^10 scale)
  const float SC = 1.0f / 1048576.0f;  // 2^-20 on probabilities
  float p[16], T = 0.0f;
#pragma unroll
  for (int r = 0; r < 16; ++r) {
    p[r] = sr[r] * sr[r] + si[r] * si[r];
    T += p[r];
  }
  float z[10];
#pragma unroll
  for (int w = 0; w < 6; ++w) {
    const int lb = 5 - w;
    z[w] = ((lane >> lb) & 1) ? -T : T;
  }
#pragma unroll
  for (int w = 6; w < 10; ++w) {
    const int rb = 9 - w;
    float s = 0.0f;
#pragma unroll
    for (int r = 0; r < 16; ++r) s += ((r >> rb) & 1) ? -p[r] : p[r];
    z[w] = s;
  }
#pragma unroll
  for (int w = 0; w < 10; ++w) z[w] = bfly_sum(z[w]) * SC;

  if (lane == 0) {
    float o0 = post_b[0], o1 = post_b[1];
#pragma unroll
    for (int w = 0; w < 10; ++w) {
      o0 += z[w] * post_w[w];
      o1 += z[w] * post_w[10 + w];
    }
    *(float2*)(out + (size_t)b * 2) = make_float2(o0, o1);
  }
}

extern "C" void kernel_launch(void* const* d_in, const int* in_sizes, int n_in,
                              void* d_out, int out_size, void* d_ws, size_t ws_size,
                              hipStream_t stream) {
  (void)n_in; (void)out_size;
  const float* x      = (const float*)d_in[0];
  const float* pre_w  = (const float*)d_in[1];
  const float* pre_b  = (const float*)d_in[2];
  const float* qp     = (const float*)d_in[3];
  const float* post_w = (const float*)d_in[4];
  const float* post_b = (const float*)d_in[5];
  float* out = (float*)d_out;

  float* tab = nullptr;
  if (ws_size >= 120 * sizeof(float)) {
    tab = (float*)d_ws;
    hipLaunchKernelGGL(dqc_trig_kernel, dim3(1), dim3(64), 0, stream, qp, tab);
  }

  const int batch = in_sizes[0] / 512;  // 16384
  dim3 grid(batch / 4), block(256);
  hipLaunchKernelGGL(dqc_kernel, grid, block, 0, stream,
                     x, pre_w, pre_b, qp, post_w, post_b, tab, out);
}

// Round 5
// 168.515 us; speedup vs baseline: 4.8331x; 1.0326x over previous
//
#include <hip/hip_runtime.h>
#include <math.h>

#define PI_F 3.14159265358979323846f

typedef float v2f __attribute__((ext_vector_type(2)));

// One wave (64 lanes) simulates one batch element's 10-qubit statevector.
// Amplitude index a (10 bits): bits[9:4] = lane, bits[3:0] = register index.
// Wire w <-> amplitude bit (9 - w) [wire 0 = MSB]. Wires 0..5 cross-lane,
// 6..9 in-register. State V[r] = (re, im) packed -> v_pk_* f32 ops.
// Cross-lane: xor1/xor2 via DPP quad_perm (VALU), xor4/8/16 via ds_swizzle,
// xor32 via shfl. CNOT cascade lane-part = Gray-code ds_bpermute.
// All H raw (+/-); 2^-20 prob scale removed in epilogue.

template <int CTRL>
__device__ __forceinline__ float dppf(float v) {
  return __int_as_float(__builtin_amdgcn_update_dpp(
      __float_as_int(v), __float_as_int(v), CTRL, 0xF, 0xF, false));
}

template <int M>
__device__ __forceinline__ float shx(float v) {
  if constexpr (M == 1) {
    return dppf<0xB1>(v);                     // quad_perm [1,0,3,2]
  } else if constexpr (M == 2) {
    return dppf<0x4E>(v);                     // quad_perm [2,3,0,1]
  } else if constexpr (M < 32) {
    return __int_as_float(
        __builtin_amdgcn_ds_swizzle(__float_as_int(v), (M << 10) | 0x1f));
  } else {
    return __shfl_xor(v, 32, 64);
  }
}

template <int M>
__device__ __forceinline__ v2f shx2(v2f v) {
  v2f r;
  r.x = shx<M>(v.x);
  r.y = shx<M>(v.y);
  return r;
}

__device__ __forceinline__ float bfly_sum(float v) {
  v += shx<1>(v); v += shx<2>(v); v += shx<4>(v);
  v += shx<8>(v); v += shx<16>(v); v += shx<32>(v);
  return v;
}

__device__ __forceinline__ float ftanh(float x) {
  float e = __expf(2.0f * x);
  return 1.0f - 2.0f / (e + 1.0f);
}

// RAW Hadamard (no 1/sqrt2)
template <int W>
__device__ __forceinline__ void apply_h(v2f (&V)[16], int lane) {
  if constexpr (W <= 5) {
    constexpr int lb = 5 - W;
    const float g = ((lane >> lb) & 1) ? -1.0f : 1.0f;
    v2f gg; gg.x = g; gg.y = g;
#pragma unroll
    for (int r = 0; r < 16; ++r) {
      v2f p = shx2<(1 << lb)>(V[r]);
      V[r] = gg * V[r] + p;
    }
  } else {
    constexpr int rb = 9 - W;
#pragma unroll
    for (int r = 0; r < 16; ++r) {
      if ((r >> rb) & 1) continue;
      const int r1 = r | (1 << rb);
      v2f a = V[r], b = V[r1];
      V[r]  = a + b;
      V[r1] = a - b;
    }
  }
}

template <int W>
__device__ __forceinline__ void apply_ry(v2f (&V)[16], int lane, float c, float s) {
  v2f cc; cc.x = c; cc.y = c;
  if constexpr (W <= 5) {
    constexpr int lb = 5 - W;
    const float t = ((lane >> lb) & 1) ? s : -s;
    v2f tt; tt.x = t; tt.y = t;
#pragma unroll
    for (int r = 0; r < 16; ++r) {
      v2f p = shx2<(1 << lb)>(V[r]);
      V[r] = cc * V[r] + tt * p;
    }
  } else {
    constexpr int rb = 9 - W;
    v2f ss; ss.x = s; ss.y = s;
#pragma unroll
    for (int r = 0; r < 16; ++r) {
      if ((r >> rb) & 1) continue;
      const int r1 = r | (1 << rb);
      v2f a = V[r], b = V[r1];
      V[r]  = cc * a - ss * b;
      V[r1] = ss * a + cc * b;
    }
  }
}

// CNOT(control=C, target=C+1), reg-side tail of the cascade
template <int C>
__device__ __forceinline__ void apply_cnot(v2f (&V)[16], int lane) {
  if constexpr (C == 5) {                     // control lane bit 0, target reg bit 3
    const bool ctrl = lane & 1;
#pragma unroll
    for (int r = 0; r < 8; ++r) {
      v2f t0 = V[r], t1 = V[r + 8];
      V[r]     = ctrl ? t1 : t0;
      V[r + 8] = ctrl ? t0 : t1;
    }
  } else {                                    // both reg bits: pure SSA renaming
    constexpr int cb = 9 - C;
    constexpr int tb = 8 - C;
#pragma unroll
    for (int r = 0; r < 16; ++r) {
      if (!(((r >> cb) & 1) && !((r >> tb) & 1))) continue;
      const int r1 = r | (1 << tb);
      v2f t = V[r]; V[r] = V[r1]; V[r1] = t;
    }
  }
}

__device__ __forceinline__ v2f bperm2(int addr, v2f v) {
  v2f r;
  r.x = __int_as_float(__builtin_amdgcn_ds_bpermute(addr, __float_as_int(v.x)));
  r.y = __int_as_float(__builtin_amdgcn_ds_bpermute(addr, __float_as_int(v.y)));
  return r;
}

// Full CNOT cascade C(0,1)..C(8,9): lane-wire part is the Gray permutation.
__device__ __forceinline__ void cascade(v2f (&V)[16], int lane) {
  const int addr = ((lane ^ (lane >> 1)) << 2);
#pragma unroll
  for (int r = 0; r < 16; ++r) V[r] = bperm2(addr, V[r]);
  apply_cnot<5>(V, lane);
  apply_cnot<6>(V, lane);
  apply_cnot<7>(V, lane);
  apply_cnot<8>(V, lane);
}

// Batch-uniform RA-layer trig table: tab[0..59] = cos(qp*0.5), tab[60..119] = sin.
__global__ void dqc_trig_kernel(const float* __restrict__ qp, float* __restrict__ tab) {
  int t = threadIdx.x;
  if (t < 60) {
    float th = qp[t] * 0.5f;
    tab[t]      = __cosf(th);
    tab[60 + t] = __sinf(th);
  }
}

__global__ __launch_bounds__(256) void dqc_kernel(
    const float* __restrict__ x, const float* __restrict__ pre_w,
    const float* __restrict__ pre_b, const float* __restrict__ q_params,
    const float* __restrict__ post_w, const float* __restrict__ post_b,
    const float* __restrict__ tab, float* __restrict__ out) {
  const int lane = threadIdx.x & 63;
  const int wave = threadIdx.x >> 6;
  const int b = blockIdx.x * 4 + wave;

  // ---------- pre layer: q_in[w] = tanh(x[b] . pre_w[w] + pre_b[w]) * pi/2
  const float* xb = x + (size_t)b * 512 + lane * 8;
  const float4 xv0 = *(const float4*)(xb);
  const float4 xv1 = *(const float4*)(xb + 4);
  float qin[10];
#pragma unroll
  for (int q = 0; q < 10; ++q) {
    const float* wp = pre_w + q * 512 + lane * 8;
    const float4 w0 = *(const float4*)(wp);
    const float4 w1 = *(const float4*)(wp + 4);
    float a = xv0.x * w0.x + xv0.y * w0.y + xv0.z * w0.z + xv0.w * w0.w +
              xv1.x * w1.x + xv1.y * w1.y + xv1.z * w1.z + xv1.w * w1.w;
    a = bfly_sum(a);
    qin[q] = ftanh(a + pre_b[q]) * (PI_F * 0.5f);
  }

  // angle constants (all wave-uniform)
  float tq[10], phi[9];
#pragma unroll
  for (int w = 0; w < 10; ++w) tq[w] = 2.0f * qin[w];
#pragma unroll
  for (int i = 0; i < 9; ++i)
    phi[i] = 2.0f * (PI_F - qin[i]) * (PI_F - qin[i + 1]);

  v2f V[16];

  // ---------- ZZFM rep 1 (analytic): amp(y) = e^{i*theta1(y)}
  {
    float A1 = 0.0f;
    int bprev = 0;
#pragma unroll
    for (int w = 0; w <= 5; ++w) {
      int bw = (lane >> (5 - w)) & 1;
      A1 += (bw ^ bprev) ? tq[w] : 0.0f;
      bprev = bw;
    }
#pragma unroll
    for (int i = 0; i <= 4; ++i)
      A1 += ((lane >> (5 - (i + 1))) & 1) ? phi[i] : 0.0f;
    const int b5 = lane & 1;
    const float m0 = A1 + (b5 ? tq[6] : 0.0f);   // for regs with bit6 = 0
    const float m1 = A1 + (b5 ? 0.0f : tq[6]);   // for regs with bit6 = 1
#pragma unroll
    for (int r = 0; r < 16; ++r) {
      const int c6 = (r >> 3) & 1, c7 = (r >> 2) & 1, c8 = (r >> 1) & 1, c9 = r & 1;
      float S = ((c6 ^ c7) ? tq[7] : 0.0f) + ((c7 ^ c8) ? tq[8] : 0.0f) +
                ((c8 ^ c9) ? tq[9] : 0.0f) +
                (c6 ? phi[5] : 0.0f) + (c7 ? phi[6] : 0.0f) +
                (c8 ? phi[7] : 0.0f) + (c9 ? phi[8] : 0.0f);
      float th = (c6 ? m1 : m0) + S;
      v2f amp; amp.x = __cosf(th); amp.y = __sinf(th);
      V[r] = amp;
    }
  }

  // ---------- ZZFM rep 2: H layer (raw), folded diagonal, cascade
  apply_h<0>(V, lane); apply_h<1>(V, lane); apply_h<2>(V, lane);
  apply_h<3>(V, lane); apply_h<4>(V, lane); apply_h<5>(V, lane);
  apply_h<6>(V, lane); apply_h<7>(V, lane); apply_h<8>(V, lane);
  apply_h<9>(V, lane);
  {
    float A2 = 0.0f;
    int pfx = 0;
#pragma unroll
    for (int w = 0; w <= 5; ++w) {
      int bw = (lane >> (5 - w)) & 1;
      A2 += bw ? tq[w] : 0.0f;
      pfx ^= bw;
      if (w >= 1) A2 += pfx ? phi[w - 1] : 0.0f;   // phi_{w-1} * p_w
    }
    const bool Lb = pfx;                           // lane parity
#pragma unroll
    for (int r = 0; r < 16; ++r) {
      const int c6 = (r >> 3) & 1, c7 = (r >> 2) & 1, c8 = (r >> 1) & 1, c9 = r & 1;
      const int q6 = c6, q7 = q6 ^ c7, q8 = q7 ^ c8, q9 = q8 ^ c9;
      float S2 = (c6 ? tq[6] : 0.0f) + (c7 ? tq[7] : 0.0f) +
                 (c8 ? tq[8] : 0.0f) + (c9 ? tq[9] : 0.0f);
      float Vv = (q6 ? phi[5] : 0.0f) + (q7 ? phi[6] : 0.0f) +
                 (q8 ? phi[7] : 0.0f) + (q9 ? phi[8] : 0.0f);
      float U = (q6 ? 0.0f : phi[5]) + (q7 ? 0.0f : phi[6]) +
                (q8 ? 0.0f : phi[7]) + (q9 ? 0.0f : phi[8]);
      float th = A2 + (Lb ? (S2 + U) : (S2 + Vv));
      float c = __cosf(th), s = __sinf(th);
      float re = V[r].x, im = V[r].y;
      V[r].x = re * c - im * s;
      V[r].y = re * s + im * c;
    }
  }
  cascade(V, lane);

  // ---------- RealAmplitudes: 6 x (RY layer + CNOT cascade)
#pragma unroll 1
  for (int l = 0; l < 6; ++l) {
    float qc[10], qs[10];
    if (tab) {
#pragma unroll
      for (int w = 0; w < 10; ++w) {
        qc[w] = tab[l * 10 + w];
        qs[w] = tab[60 + l * 10 + w];
      }
    } else {
#pragma unroll
      for (int w = 0; w < 10; ++w) {
        float th = q_params[l * 10 + w] * 0.5f;
        qc[w] = __cosf(th);
        qs[w] = __sinf(th);
      }
    }
#define RYW(W) apply_ry<W>(V, lane, qc[W], qs[W]);
    RYW(0) RYW(1) RYW(2) RYW(3) RYW(4) RYW(5) RYW(6) RYW(7) RYW(8) RYW(9)
#undef RYW
    cascade(V, lane);
  }

  // ---------- epilogue: out = (sum_r p_r * (G(lane) + K[r])) reduced, * 2^-20
  // z_w (w<6) sign depends on lane bits -> G(lane); w>=6 sign on reg bits -> K[r].
  const float SC = 1.0f / 1048576.0f;
  const float pw06 = post_w[6], pw07 = post_w[7], pw08 = post_w[8], pw09 = post_w[9];
  const float pw16 = post_w[16], pw17 = post_w[17], pw18 = post_w[18], pw19 = post_w[19];
  float k89a[4], k89b[4];
  {
    float a0 = pw08 + pw09, a1 = pw08 - pw09;
    k89a[0] = a0; k89a[1] = a1; k89a[2] = -a1; k89a[3] = -a0;
    float b0 = pw18 + pw19, b1 = pw18 - pw19;
    k89b[0] = b0; k89b[1] = b1; k89b[2] = -b1; k89b[3] = -b0;
  }
  float K0[16], K1[16];
#pragma unroll
  for (int r = 0; r < 16; ++r) {
    K0[r] = ((r & 8) ? -pw06 : pw06) + ((r & 4) ? -pw07 : pw07) + k89a[r & 3];
    K1[r] = ((r & 8) ? -pw16 : pw16) + ((r & 4) ? -pw17 : pw17) + k89b[r & 3];
  }
  float G0 = 0.0f, G1 = 0.0f;
#pragma unroll
  for (int w = 0; w < 6; ++w) {
    const bool n = (lane >> (5 - w)) & 1;
    const float pa = post_w[w], pb = post_w[10 + w];
    G0 += n ? -pa : pa;
    G1 += n ? -pb : pb;
  }
  float o0 = 0.0f, o1 = 0.0f;
#pragma unroll
  for (int r = 0; r < 16; ++r) {
    v2f t = V[r] * V[r];
    float p = t.x + t.y;
    o0 = fmaf(p, G0 + K0[r], o0);
    o1 = fmaf(p, G1 + K1[r], o1);
  }
  o0 = bfly_sum(o0);
  o1 = bfly_sum(o1);

  if (lane == 0) {
    *(float2*)(out + (size_t)b * 2) =
        make_float2(o0 * SC + post_b[0], o1 * SC + post_b[1]);
  }
}

extern "C" void kernel_launch(void* const* d_in, const int* in_sizes, int n_in,
                              void* d_out, int out_size, void* d_ws, size_t ws_size,
                              hipStream_t stream) {
  (void)n_in; (void)out_size;
  const float* x      = (const float*)d_in[0];
  const float* pre_w  = (const float*)d_in[1];
  const float* pre_b  = (const float*)d_in[2];
  const float* qp     = (const float*)d_in[3];
  const float* post_w = (const float*)d_in[4];
  const float* post_b = (const float*)d_in[5];
  float* out = (float*)d_out;

  float* tab = nullptr;
  if (ws_size >= 120 * sizeof(float)) {
    tab = (float*)d_ws;
    hipLaunchKernelGGL(dqc_trig_kernel, dim3(1), dim3(64), 0, stream, qp, tab);
  }

  const int batch = in_sizes[0] / 512;  // 16384
  dim3 grid(batch / 4), block(256);
  hipLaunchKernelGGL(dqc_kernel, grid, block, 0, stream,
                     x, pre_w, pre_b, qp, post_w, post_b, tab, out);
}

// Round 6
// 166.754 us; speedup vs baseline: 4.8841x; 1.0106x over previous
//
#include <hip/hip_runtime.h>
#include <math.h>

#define PI_F 3.14159265358979323846f

typedef float v2f __attribute__((ext_vector_type(2)));

// One wave = one batch element's 10-qubit statevector.
// Amp index bits[9:4]=lane, bits[3:0]=reg. Wire w <-> bit (9-w).
// Wires 0..5 cross-lane (w0:shfl32, w1:ds_swz16, w2:DPP row_ror:8,
// w3:ds_swz4, w4/w5: DPP quad_perm), wires 6..9 in-register.
// State V[r]=(re,im) -> TRUE packed math via inline-asm v_pk_*_f32.
// CNOT cascade lane-part = Gray-code ds_bpermute. H raw; 2^-20 in epilogue.

__device__ __forceinline__ v2f pk_fma(v2f a, v2f b, v2f c) {
  v2f d;
  asm("v_pk_fma_f32 %0, %1, %2, %3" : "=v"(d) : "v"(a), "v"(b), "v"(c));
  return d;
}
__device__ __forceinline__ v2f pk_mul(v2f a, v2f b) {
  v2f d;
  asm("v_pk_mul_f32 %0, %1, %2" : "=v"(d) : "v"(a), "v"(b));
  return d;
}
__device__ __forceinline__ v2f pk_add(v2f a, v2f b) {
  v2f d;
  asm("v_pk_add_f32 %0, %1, %2" : "=v"(d) : "v"(a), "v"(b));
  return d;
}

template <int CTRL>
__device__ __forceinline__ float dppf(float v) {
  return __int_as_float(__builtin_amdgcn_update_dpp(
      __float_as_int(v), __float_as_int(v), CTRL, 0xF, 0xF, false));
}

template <int M>
__device__ __forceinline__ float shx(float v) {
  if constexpr (M == 1) {
    return dppf<0xB1>(v);                     // quad_perm [1,0,3,2]
  } else if constexpr (M == 2) {
    return dppf<0x4E>(v);                     // quad_perm [2,3,0,1]
  } else if constexpr (M == 8) {
    return dppf<0x128>(v);                    // row_ror:8 == xor 8 in 16-row
  } else if constexpr (M < 32) {
    return __int_as_float(
        __builtin_amdgcn_ds_swizzle(__float_as_int(v), (M << 10) | 0x1f));
  } else {
    return __shfl_xor(v, 32, 64);
  }
}

template <int M>
__device__ __forceinline__ v2f shx2(v2f v) {
  v2f r;
  r.x = shx<M>(v.x);
  r.y = shx<M>(v.y);
  return r;
}

__device__ __forceinline__ float bfly_sum(float v) {
  v += shx<1>(v); v += shx<2>(v); v += shx<4>(v);
  v += shx<8>(v); v += shx<16>(v); v += shx<32>(v);
  return v;
}

__device__ __forceinline__ float ftanh(float x) {
  float e = __expf(2.0f * x);
  return 1.0f - 2.0f / (e + 1.0f);
}

__device__ __forceinline__ v2f vsplat(float a) { v2f r; r.x = a; r.y = a; return r; }

// RAW Hadamard (no 1/sqrt2)
template <int W>
__device__ __forceinline__ void apply_h(v2f (&V)[16], int lane, v2f M1) {
  if constexpr (W <= 5) {
    constexpr int lb = 5 - W;
    const v2f gg = vsplat(((lane >> lb) & 1) ? -1.0f : 1.0f);
#pragma unroll
    for (int r = 0; r < 16; ++r) {
      v2f p = shx2<(1 << lb)>(V[r]);
      V[r] = pk_fma(gg, V[r], p);             // p + (+/-1)*V
    }
  } else {
    constexpr int rb = 9 - W;
#pragma unroll
    for (int r = 0; r < 16; ++r) {
      if ((r >> rb) & 1) continue;
      const int r1 = r | (1 << rb);
      v2f a = V[r], b = V[r1];
      V[r]  = pk_add(a, b);
      V[r1] = pk_fma(b, M1, a);               // a - b
    }
  }
}

// RY: c,s wave-uniform; ssn = -s splat
template <int W>
__device__ __forceinline__ void apply_ry(v2f (&V)[16], int lane,
                                         v2f cc, v2f ss, v2f ssn) {
  if constexpr (W <= 5) {
    constexpr int lb = 5 - W;
    const v2f tt = ((lane >> lb) & 1) ? ss : ssn;
#pragma unroll
    for (int r = 0; r < 16; ++r) {
      v2f p = shx2<(1 << lb)>(V[r]);
      V[r] = pk_fma(tt, p, pk_mul(cc, V[r]));
    }
  } else {
    constexpr int rb = 9 - W;
#pragma unroll
    for (int r = 0; r < 16; ++r) {
      if ((r >> rb) & 1) continue;
      const int r1 = r | (1 << rb);
      v2f a = V[r], b = V[r1];
      V[r]  = pk_fma(ssn, b, pk_mul(cc, a));  // c*a - s*b
      V[r1] = pk_fma(ss,  a, pk_mul(cc, b));  // s*a + c*b
    }
  }
}

// CNOT(control=C, target=C+1), reg-side tail of the cascade
template <int C>
__device__ __forceinline__ void apply_cnot(v2f (&V)[16], int lane) {
  if constexpr (C == 5) {                     // control lane bit 0, target reg bit 3
    const bool ctrl = lane & 1;
#pragma unroll
    for (int r = 0; r < 8; ++r) {
      v2f t0 = V[r], t1 = V[r + 8];
      V[r]     = ctrl ? t1 : t0;
      V[r + 8] = ctrl ? t0 : t1;
    }
  } else {                                    // both reg bits: pure SSA renaming
    constexpr int cb = 9 - C;
    constexpr int tb = 8 - C;
#pragma unroll
    for (int r = 0; r < 16; ++r) {
      if (!(((r >> cb) & 1) && !((r >> tb) & 1))) continue;
      const int r1 = r | (1 << tb);
      v2f t = V[r]; V[r] = V[r1]; V[r1] = t;
    }
  }
}

__device__ __forceinline__ v2f bperm2(int addr, v2f v) {
  v2f r;
  r.x = __int_as_float(__builtin_amdgcn_ds_bpermute(addr, __float_as_int(v.x)));
  r.y = __int_as_float(__builtin_amdgcn_ds_bpermute(addr, __float_as_int(v.y)));
  return r;
}

// Full CNOT cascade C(0,1)..C(8,9): lane-wire part is the Gray permutation.
__device__ __forceinline__ void cascade(v2f (&V)[16], int lane) {
  const int addr = ((lane ^ (lane >> 1)) << 2);
#pragma unroll
  for (int r = 0; r < 16; ++r) V[r] = bperm2(addr, V[r]);
  apply_cnot<5>(V, lane);
  apply_cnot<6>(V, lane);
  apply_cnot<7>(V, lane);
  apply_cnot<8>(V, lane);
}

// Batch-uniform RA-layer trig table: tab[0..59] = cos(qp*0.5), tab[60..119] = sin.
__global__ void dqc_trig_kernel(const float* __restrict__ qp, float* __restrict__ tab) {
  int t = threadIdx.x;
  if (t < 60) {
    float th = qp[t] * 0.5f;
    tab[t]      = __cosf(th);
    tab[60 + t] = __sinf(th);
  }
}

__global__ __launch_bounds__(256) void dqc_kernel(
    const float* __restrict__ x, const float* __restrict__ pre_w,
    const float* __restrict__ pre_b, const float* __restrict__ q_params,
    const float* __restrict__ post_w, const float* __restrict__ post_b,
    const float* __restrict__ tab, float* __restrict__ out) {
  const int lane = threadIdx.x & 63;
  const int wave = threadIdx.x >> 6;
  const int b = blockIdx.x * 4 + wave;
  const v2f M1 = vsplat(-1.0f);

  // ---------- pre layer: q_in[w] = tanh(x[b] . pre_w[w] + pre_b[w]) * pi/2
  const float* xb = x + (size_t)b * 512 + lane * 8;
  const float4 xv0 = *(const float4*)(xb);
  const float4 xv1 = *(const float4*)(xb + 4);
  float qin[10];
#pragma unroll
  for (int q = 0; q < 10; ++q) {
    const float* wp = pre_w + q * 512 + lane * 8;
    const float4 w0 = *(const float4*)(wp);
    const float4 w1 = *(const float4*)(wp + 4);
    float a = xv0.x * w0.x + xv0.y * w0.y + xv0.z * w0.z + xv0.w * w0.w +
              xv1.x * w1.x + xv1.y * w1.y + xv1.z * w1.z + xv1.w * w1.w;
    a = bfly_sum(a);
    qin[q] = ftanh(a + pre_b[q]) * (PI_F * 0.5f);
  }

  // angle constants (all wave-uniform)
  float tq[10], phi[9];
#pragma unroll
  for (int w = 0; w < 10; ++w) tq[w] = 2.0f * qin[w];
#pragma unroll
  for (int i = 0; i < 9; ++i)
    phi[i] = 2.0f * (PI_F - qin[i]) * (PI_F - qin[i + 1]);

  v2f V[16];

  // ---------- ZZFM rep 1 (analytic): amp(y) = e^{i*theta1(y)}
  {
    float A1 = 0.0f;
    int bprev = 0;
#pragma unroll
    for (int w = 0; w <= 5; ++w) {
      int bw = (lane >> (5 - w)) & 1;
      A1 += (bw ^ bprev) ? tq[w] : 0.0f;
      bprev = bw;
    }
#pragma unroll
    for (int i = 0; i <= 4; ++i)
      A1 += ((lane >> (5 - (i + 1))) & 1) ? phi[i] : 0.0f;
    const int b5 = lane & 1;
    const float m0 = A1 + (b5 ? tq[6] : 0.0f);   // regs with bit6 = 0
    const float m1 = A1 + (b5 ? 0.0f : tq[6]);   // regs with bit6 = 1
#pragma unroll
    for (int r = 0; r < 16; ++r) {
      const int c6 = (r >> 3) & 1, c7 = (r >> 2) & 1, c8 = (r >> 1) & 1, c9 = r & 1;
      float S = ((c6 ^ c7) ? tq[7] : 0.0f) + ((c7 ^ c8) ? tq[8] : 0.0f) +
                ((c8 ^ c9) ? tq[9] : 0.0f) +
                (c6 ? phi[5] : 0.0f) + (c7 ? phi[6] : 0.0f) +
                (c8 ? phi[7] : 0.0f) + (c9 ? phi[8] : 0.0f);
      float th = (c6 ? m1 : m0) + S;
      v2f amp; amp.x = __cosf(th); amp.y = __sinf(th);
      V[r] = amp;
    }
  }

  // ---------- ZZFM rep 2: H layer (raw, gates commute -> interleave pipes)
  apply_h<0>(V, lane, M1); apply_h<6>(V, lane, M1);
  apply_h<1>(V, lane, M1); apply_h<7>(V, lane, M1);
  apply_h<3>(V, lane, M1); apply_h<8>(V, lane, M1);
  apply_h<2>(V, lane, M1); apply_h<9>(V, lane, M1);
  apply_h<4>(V, lane, M1); apply_h<5>(V, lane, M1);
  {
    float A2 = 0.0f;
    int pfx = 0;
#pragma unroll
    for (int w = 0; w <= 5; ++w) {
      int bw = (lane >> (5 - w)) & 1;
      A2 += bw ? tq[w] : 0.0f;
      pfx ^= bw;
      if (w >= 1) A2 += pfx ? phi[w - 1] : 0.0f;   // phi_{w-1} * p_w
    }
    const bool Lb = pfx;                           // lane parity
#pragma unroll
    for (int r = 0; r < 16; ++r) {
      const int c6 = (r >> 3) & 1, c7 = (r >> 2) & 1, c8 = (r >> 1) & 1, c9 = r & 1;
      const int q6 = c6, q7 = q6 ^ c7, q8 = q7 ^ c8, q9 = q8 ^ c9;
      float S2 = (c6 ? tq[6] : 0.0f) + (c7 ? tq[7] : 0.0f) +
                 (c8 ? tq[8] : 0.0f) + (c9 ? tq[9] : 0.0f);
      float Vv = (q6 ? phi[5] : 0.0f) + (q7 ? phi[6] : 0.0f) +
                 (q8 ? phi[7] : 0.0f) + (q9 ? phi[8] : 0.0f);
      float U = (q6 ? 0.0f : phi[5]) + (q7 ? 0.0f : phi[6]) +
                (q8 ? 0.0f : phi[7]) + (q9 ? 0.0f : phi[8]);
      float th = A2 + (Lb ? (S2 + U) : (S2 + Vv));
      float c = __cosf(th), s = __sinf(th);
      float re = V[r].x, im = V[r].y;
      V[r].x = re * c - im * s;
      V[r].y = re * s + im * c;
    }
  }
  cascade(V, lane);

  // ---------- RealAmplitudes: 6 x (RY layer + CNOT cascade)
#pragma unroll 1
  for (int l = 0; l < 6; ++l) {
    v2f qc[10], qs[10], qsn[10];
    if (tab) {
#pragma unroll
      for (int w = 0; w < 10; ++w) {
        float c = tab[l * 10 + w], s = tab[60 + l * 10 + w];
        qc[w] = vsplat(c); qs[w] = vsplat(s); qsn[w] = vsplat(-s);
      }
    } else {
#pragma unroll
      for (int w = 0; w < 10; ++w) {
        float th = q_params[l * 10 + w] * 0.5f;
        float c = __cosf(th), s = __sinf(th);
        qc[w] = vsplat(c); qs[w] = vsplat(s); qsn[w] = vsplat(-s);
      }
    }
#define RYW(W) apply_ry<W>(V, lane, qc[W], qs[W], qsn[W]);
    // gates commute: interleave DS-wire (0,1,3) / DPP-wire (2,4,5) / reg (6-9)
    RYW(0) RYW(6) RYW(1) RYW(7) RYW(3) RYW(8) RYW(2) RYW(9) RYW(4) RYW(5)
#undef RYW
    cascade(V, lane);
  }

  // ---------- epilogue: out = (sum_r p_r * (G(lane) + K[r])) reduced, * 2^-20
  const float SC = 1.0f / 1048576.0f;
  const float pw06 = post_w[6], pw07 = post_w[7], pw08 = post_w[8], pw09 = post_w[9];
  const float pw16 = post_w[16], pw17 = post_w[17], pw18 = post_w[18], pw19 = post_w[19];
  float k89a[4], k89b[4];
  {
    float a0 = pw08 + pw09, a1 = pw08 - pw09;
    k89a[0] = a0; k89a[1] = a1; k89a[2] = -a1; k89a[3] = -a0;
    float b0 = pw18 + pw19, b1 = pw18 - pw19;
    k89b[0] = b0; k89b[1] = b1; k89b[2] = -b1; k89b[3] = -b0;
  }
  float G0 = 0.0f, G1 = 0.0f;
#pragma unroll
  for (int w = 0; w < 6; ++w) {
    const bool n = (lane >> (5 - w)) & 1;
    const float pa = post_w[w], pb = post_w[10 + w];
    G0 += n ? -pa : pa;
    G1 += n ? -pb : pb;
  }
  float o0 = 0.0f, o1 = 0.0f;
#pragma unroll
  for (int r = 0; r < 16; ++r) {
    const float K0 = ((r & 8) ? -pw06 : pw06) + ((r & 4) ? -pw07 : pw07) + k89a[r & 3];
    const float K1 = ((r & 8) ? -pw16 : pw16) + ((r & 4) ? -pw17 : pw17) + k89b[r & 3];
    v2f t = pk_mul(V[r], V[r]);
    float p = t.x + t.y;
    o0 = fmaf(p, G0 + K0, o0);
    o1 = fmaf(p, G1 + K1, o1);
  }
  o0 = bfly_sum(o0);
  o1 = bfly_sum(o1);

  if (lane == 0) {
    *(float2*)(out + (size_t)b * 2) =
        make_float2(o0 * SC + post_b[0], o1 * SC + post_b[1]);
  }
}

extern "C" void kernel_launch(void* const* d_in, const int* in_sizes, int n_in,
                              void* d_out, int out_size, void* d_ws, size_t ws_size,
                              hipStream_t stream) {
  (void)n_in; (void)out_size;
  const float* x      = (const float*)d_in[0];
  const float* pre_w  = (const float*)d_in[1];
  const float* pre_b  = (const float*)d_in[2];
  const float* qp     = (const float*)d_in[3];
  const float* post_w = (const float*)d_in[4];
  const float* post_b = (const float*)d_in[5];
  float* out = (float*)d_out;

  float* tab = nullptr;
  if (ws_size >= 120 * sizeof(float)) {
    tab = (float*)d_ws;
    hipLaunchKernelGGL(dqc_trig_kernel, dim3(1), dim3(64), 0, stream, qp, tab);
  }

  const int batch = in_sizes[0] / 512;  // 16384
  dim3 grid(batch / 4), block(256);
  hipLaunchKernelGGL(dqc_kernel, grid, block, 0, stream,
                     x, pre_w, pre_b, qp, post_w, post_b, tab, out);
}